// Round 8
// baseline (124.609 us; speedup 1.0000x reference)
//
#include <hip/hip_runtime.h>
#include <math.h>

// MAM fully-connected: out[r][o] = max_k(x[r][k]*W[o][k]) + min_k(x[r][k]*W[o][k]) + b[o]
// x: (1024, 512) f32, W: (512, 512) f32, b: (512,), out: (1024, 512) f32.
//
// v8: ZERO-LDS / ZERO-BARRIER. All prior versions (21-26us) shared per-phase
// __syncthreads (vmcnt(0) drain stalls) + DS-pipe W streaming. Here:
//  - wave = 8 outs x 8 K-segments; lane (o=og*8+(l>>3), s=l&7) holds its W
//    fragment (64 floats = 16 float4 = 64 VGPRs) loaded ONCE from global
//  - per row: 32 v_pk_mul_f32 + 4 interleaved max3/min3 chains (2 ops/product
//    after packing), then 3-step ds_swizzle butterfly (xor 1,2,4) all-reduce
//    across the 8 seg-lanes; lane s==0 stores. No __shared__, no barriers.
//  - 1024 blocks x 4 waves = 16 waves/CU; launch_bounds(256,3) caps VGPR at
//    ~170 so the W fragment provably fits without spill.
// Issue floor ~5.6us/SIMD; DS swizzles ~3.8us/CU on the parallel pipe.

#define O_TOTAL 512
#define K_TOTAL 512
#define OPW 8                    // outs per wave
#define KSEG 64                  // k per segment (8 segs * 64 = 512)
#define RPW 16                   // rows per wave
#define NJ 16                    // float4 groups per segment

typedef float f32x2 __attribute__((ext_vector_type(2)));

__device__ __forceinline__ f32x2 pk_mul(f32x2 a, f32x2 b) {
  f32x2 d;
  asm("v_pk_mul_f32 %0, %1, %2" : "=v"(d) : "v"(a), "v"(b));
  return d;
}

// ds_swizzle BitMode: offset = (xor_mask<<10) | (or_mask<<5) | and_mask(0x1F)
#define SWZ_XOR1 0x041F
#define SWZ_XOR2 0x081F
#define SWZ_XOR4 0x101F
#define SWZF(v, pat) __int_as_float(__builtin_amdgcn_ds_swizzle(__float_as_int(v), (pat)))

__global__ __launch_bounds__(256, 3)
void mam_fc_kernel(const float* __restrict__ x, const float* __restrict__ W,
                   const float* __restrict__ bias, float* __restrict__ out) {
  const int t = threadIdx.x;
  const int lane = t & 63;
  const int wv = t >> 6;
  const int g = lane >> 3;              // out within wave's 8-out group
  const int s = lane & 7;               // k-segment

  const int ogq = blockIdx.x & 15;      // 16 quads of out-groups
  const int rc  = blockIdx.x >> 4;      // 64 row-chunks of 16
  const int og  = ogq * 4 + wv;         // out-group 0..63
  const int o   = og * OPW + g;         // this lane's out neuron
  const int rbase = rc * RPW;

  // ---- W fragment -> 16 float4 in VGPRs, loaded once, reused for 16 rows ----
  const float* wp = W + (size_t)o * K_TOTAL + s * KSEG;
  float4 w[NJ];
#pragma unroll
  for (int j = 0; j < NJ; ++j)
    w[j] = *reinterpret_cast<const float4*>(wp + j * 4);

  const float bv = bias[o];
  const float* xp = x + (size_t)rbase * K_TOTAL + s * KSEG;
  float* op = out + (size_t)rbase * O_TOTAL + o;

#pragma unroll
  for (int r = 0; r < RPW; ++r) {
    const float* xr = xp + (size_t)r * K_TOTAL;
    // j = 0 seeds the 4 independent chains
    float4 xq = *reinterpret_cast<const float4*>(xr);
    f32x2 a = pk_mul(f32x2{xq.x, xq.y}, f32x2{w[0].x, w[0].y});
    f32x2 b = pk_mul(f32x2{xq.z, xq.w}, f32x2{w[0].z, w[0].w});
    float m0 = fmaxf(a.x, a.y), n0 = fminf(a.x, a.y);
    float m1 = fmaxf(b.x, b.y), n1 = fminf(b.x, b.y);
#pragma unroll
    for (int j = 1; j < NJ; ++j) {
      xq = *reinterpret_cast<const float4*>(xr + j * 4);
      a = pk_mul(f32x2{xq.x, xq.y}, f32x2{w[j].x, w[j].y});
      b = pk_mul(f32x2{xq.z, xq.w}, f32x2{w[j].z, w[j].w});
      // fmax(fmax(m,ax),ay) -> v_max3_f32
      m0 = fmaxf(fmaxf(m0, a.x), a.y);
      n0 = fminf(fminf(n0, a.x), a.y);
      m1 = fmaxf(fmaxf(m1, b.x), b.y);
      n1 = fminf(fminf(n1, b.x), b.y);
    }
    float m = fmaxf(m0, m1);
    float n = fminf(n0, n1);
    // all-reduce across the 8 seg-lanes (partners within 32-lane halves)
    m = fmaxf(m, SWZF(m, SWZ_XOR1));  n = fminf(n, SWZF(n, SWZ_XOR1));
    m = fmaxf(m, SWZF(m, SWZ_XOR2));  n = fminf(n, SWZF(n, SWZ_XOR2));
    m = fmaxf(m, SWZF(m, SWZ_XOR4));  n = fminf(n, SWZF(n, SWZ_XOR4));
    if (s == 0) op[(size_t)r * O_TOTAL] = m + n + bv;  // 8 lanes, 32B contiguous
  }
}

extern "C" void kernel_launch(void* const* d_in, const int* in_sizes, int n_in,
                              void* d_out, int out_size, void* d_ws, size_t ws_size,
                              hipStream_t stream) {
  const float* x = (const float*)d_in[0];    // (1024, 512)
  const float* W = (const float*)d_in[1];    // (512, 512)
  const float* b = (const float*)d_in[2];    // (512,)
  float* out = (float*)d_out;                // (1024, 512)

  const int nrows = in_sizes[0] / K_TOTAL;                    // 1024
  const int nblocks = (O_TOTAL / (OPW * 8)) * (nrows / RPW) * 16 / 16 * 16;
  // out-group quads (16) x row-chunks (nrows/RPW)
  const int grid = 16 * (nrows / RPW);                        // 16 * 64 = 1024
  (void)nblocks;
  mam_fc_kernel<<<dim3(grid), dim3(256), 0, stream>>>(x, W, b, out);
}